// Round 3
// baseline (318.097 us; speedup 1.0000x reference)
//
#include <hip/hip_runtime.h>
#include <hip/hip_cooperative_groups.h>
#include <math.h>

namespace cg = cooperative_groups;

#define NN 512
#define FF 64
#define HH 4

// ws layout (floats):
// dinv[512] @0 ; psum[32*512] @512 ; T[4*4*512] @16896 ;
// q_t[4*4*512*64] @25088 ; kT[4*4*64*512] @2122240 ; sxd[4*512*64] @4219392

__global__ __launch_bounds__(256, 4) void k_fused(
    const float* __restrict__ x, const float* __restrict__ adj,
    const float* __restrict__ Wq, const float* __restrict__ bq,
    const float* __restrict__ Wk, const float* __restrict__ bk,
    const float* __restrict__ Wlin, const float* __restrict__ blin,
    const float* __restrict__ Wfc, const float* __restrict__ bfc,
    float* __restrict__ out,
    float* __restrict__ dinv, float* __restrict__ psum,
    float* __restrict__ T, float* __restrict__ q_t,
    float* __restrict__ kT, float* __restrict__ sxd)
{
    cg::grid_group grid = cg::this_grid();
    const int blk = blockIdx.x, tid = threadIdx.x;
    const int nb = gridDim.x;
    const int wv = tid >> 6, lane = tid & 63;

    __shared__ float x_lds[4][64];
    __shared__ float q_lds[8][64];
    __shared__ float red[8][4];
    __shared__ float red2[8][4];
    __shared__ float part[4][2][64];
    __shared__ float m_lds[2][64];
    __shared__ float part2[4][2][64];

    // ---------------- Phase A: dinv, zero T, q/k projection ----------------
    for (int gw = blk * 4 + wv; gw < NN; gw += nb * 4) {
        float acc = 0.f;
#pragma unroll
        for (int k = 0; k < 8; ++k) acc += adj[gw * NN + k * 64 + lane];
        for (int o = 32; o > 0; o >>= 1) acc += __shfl_xor(acc, o);
        if (lane == 0) dinv[gw] = 1.0f / sqrtf(acc + 1.0f);
    }
    for (int t = blk * 256 + tid; t < 4 * HH * NN; t += nb * 256) T[t] = 0.f;

    for (int u = blk; u < 1024; u += nb) {
        int b = u >> 8, rest = u & 255, isK = rest >> 7, itile = rest & 127;
        int i0 = itile * 4;
        __syncthreads();
        x_lds[tid >> 6][tid & 63] = x[((long)b * NN + i0 + (tid >> 6)) * FF + (tid & 63)];
        __syncthreads();
        const float* W = isK ? Wk : Wq;
        float bv = (isK ? bk : bq)[tid];
        float a0 = bv, a1 = bv, a2 = bv, a3 = bv;
        for (int cc = 0; cc < 64; ++cc) {
            float w = W[cc * 256 + tid];
            a0 = fmaf(x_lds[0][cc], w, a0);
            a1 = fmaf(x_lds[1][cc], w, a1);
            a2 = fmaf(x_lds[2][cc], w, a2);
            a3 = fmaf(x_lds[3][cc], w, a3);
        }
        int h = tid >> 6, f = tid & 63;
        int bh = b * HH + h;
        if (!isK) {
            long base = ((long)bh * NN + i0) * FF + f;
            q_t[base] = a0; q_t[base + FF] = a1;
            q_t[base + 2 * FF] = a2; q_t[base + 3 * FF] = a3;
        } else {
            long base = ((long)bh * FF + f) * NN + i0;  // i0%4==0 -> 16B aligned
            *(float4*)(kT + base) = make_float4(a0, a1, a2, a3);
        }
    }
    grid.sync();

    // ---------------- Phase B: csum partials + scores -> T (atomics) -------
    for (int u = blk; u < 32; u += nb) {
        int j0 = tid, j1 = tid + 256;
        float a0 = 0.f, a1 = 0.f;
#pragma unroll
        for (int ii = 0; ii < 16; ++ii) {
            int i = u * 16 + ii;
            float di = dinv[i];
            a0 = fmaf(di, adj[i * NN + j0], a0);
            a1 = fmaf(di, adj[i * NN + j1], a1);
        }
        psum[u * NN + j0] = a0;
        psum[u * NN + j1] = a1;
    }

    for (int u = blk; u < 1024; u += nb) {
        int itile = u & 63, h = (u >> 6) & 3, b = u >> 8;
        int bh = b * HH + h, i0 = itile * 8;
        __syncthreads();
#pragma unroll
        for (int k = 0; k < 2; ++k) {
            int idx = k * 256 + tid;
            q_lds[idx >> 6][idx & 63] =
                q_t[((long)bh * NN + i0 + (idx >> 6)) * FF + (idx & 63)];
        }
        __syncthreads();
        int j0 = tid, j1 = tid + 256;
        const float* kb = kT + (long)bh * FF * NN;
        float s0[8], s1[8];
#pragma unroll
        for (int r = 0; r < 8; ++r) { s0[r] = 0.f; s1[r] = 0.f; }
        for (int f4 = 0; f4 < 64; f4 += 4) {
            float kv0[4], kv1[4];
#pragma unroll
            for (int uu = 0; uu < 4; ++uu) {
                kv0[uu] = kb[(f4 + uu) * NN + j0];
                kv1[uu] = kb[(f4 + uu) * NN + j1];
            }
#pragma unroll
            for (int r = 0; r < 8; ++r) {
                float4 qv = *(const float4*)&q_lds[r][f4];
                s0[r] = fmaf(qv.x, kv0[0], s0[r]);
                s0[r] = fmaf(qv.y, kv0[1], s0[r]);
                s0[r] = fmaf(qv.z, kv0[2], s0[r]);
                s0[r] = fmaf(qv.w, kv0[3], s0[r]);
                s1[r] = fmaf(qv.x, kv1[0], s1[r]);
                s1[r] = fmaf(qv.y, kv1[1], s1[r]);
                s1[r] = fmaf(qv.z, kv1[2], s1[r]);
                s1[r] = fmaf(qv.w, kv1[3], s1[r]);
            }
        }
        const float scale = 0.125f;   // 1/sqrt(64)
        float m[8];
#pragma unroll
        for (int r = 0; r < 8; ++r) {
            float v = fmaxf(s0[r], s1[r]);
            for (int o = 32; o > 0; o >>= 1) v = fmaxf(v, __shfl_xor(v, o));
            if (lane == 0) red[r][wv] = v;
        }
        __syncthreads();
#pragma unroll
        for (int r = 0; r < 8; ++r)
            m[r] = fmaxf(fmaxf(red[r][0], red[r][1]), fmaxf(red[r][2], red[r][3]));
#pragma unroll
        for (int r = 0; r < 8; ++r) {
            s0[r] = expf((s0[r] - m[r]) * scale);
            s1[r] = expf((s1[r] - m[r]) * scale);
            float v = s0[r] + s1[r];
            for (int o = 32; o > 0; o >>= 1) v += __shfl_xor(v, o);
            if (lane == 0) red2[r][wv] = v;
        }
        __syncthreads();
        float dj0 = dinv[j0], dj1 = dinv[j1];
        float pw0 = 0.f, pw1 = 0.f;
#pragma unroll
        for (int r = 0; r < 8; ++r) {
            float Zi = 1.0f / (red2[r][0] + red2[r][1] + red2[r][2] + red2[r][3]);
            int gi = i0 + r;
            float di = dinv[gi];
            float a0 = adj[(long)gi * NN + j0] + (gi == j0 ? 1.f : 0.f);
            float a1 = adj[(long)gi * NN + j1] + (gi == j1 ? 1.f : 0.f);
            pw0 += di * a0 * s0[r] * Zi;
            pw1 += di * a1 * s1[r] * Zi;
        }
        atomicAdd(&T[bh * NN + j0], pw0 * dj0);
        atomicAdd(&T[bh * NN + j1], pw1 * dj1);
    }
    grid.sync();

    // ---------------- Phase C: sxd ----------------
    for (int t = blk * 256 + tid; t < 4 * NN * FF; t += nb * 256) {
        int f = t & 63, j = (t >> 6) & (NN - 1), b = t >> 15;
        float cs = 0.f;
#pragma unroll
        for (int p = 0; p < 32; ++p) cs += psum[p * NN + j];
        float dj = dinv[j];
        float cj = dj * (cs + dj);
        float S = blin[f] * cj;
#pragma unroll
        for (int h = 0; h < HH; ++h) S += T[(b * HH + h) * NN + j] * Wlin[h * FF + f];
        sxd[t] = x[t] * S * dj;
    }
    grid.sync();

    // ---------------- Phase D: final SpMM + FC + ReLU ----------------
    for (int u = blk; u < 1024; u += nb) {
        int b = u >> 8, itile = u & 255;
        int i0 = itile * 2;
        int f = tid & 63, jc = tid >> 6;
        const float* sb = sxd + (long)b * NN * FF + f;
        const float* ar0 = adj + (long)i0 * NN;
        const float* ar1 = ar0 + NN;
        float a0 = 0.f, a1 = 0.f;
        int jb = jc * 128;
#pragma unroll 4
        for (int j = jb; j < jb + 128; ++j) {
            float v = sb[(long)j * FF];
            a0 = fmaf(ar0[j], v, a0);
            a1 = fmaf(ar1[j], v, a1);
        }
        if ((i0 >> 7) == jc) a0 += sb[(long)i0 * FF];
        if (((i0 + 1) >> 7) == jc) a1 += sb[(long)(i0 + 1) * FF];
        __syncthreads();
        part[jc][0][f] = a0;
        part[jc][1][f] = a1;
        __syncthreads();
        if (jc == 0) {
            m_lds[0][f] = (part[0][0][f] + part[1][0][f] + part[2][0][f] + part[3][0][f]) * dinv[i0];
            m_lds[1][f] = (part[0][1][f] + part[1][1][f] + part[2][1][f] + part[3][1][f]) * dinv[i0 + 1];
        }
        __syncthreads();
        float o0 = 0.f, o1 = 0.f;
        int c0 = jc * 16;
#pragma unroll
        for (int cc = 0; cc < 16; ++cc) {
            float w = Wfc[(c0 + cc) * FF + f];
            o0 = fmaf(m_lds[0][c0 + cc], w, o0);
            o1 = fmaf(m_lds[1][c0 + cc], w, o1);
        }
        part2[jc][0][f] = o0;
        part2[jc][1][f] = o1;
        __syncthreads();
        if (jc == 0) {
            float bb = bfc[f];
            float r0 = part2[0][0][f] + part2[1][0][f] + part2[2][0][f] + part2[3][0][f] + bb;
            float r1 = part2[0][1][f] + part2[1][1][f] + part2[2][1][f] + part2[3][1][f] + bb;
            out[((long)b * NN + i0) * FF + f]     = fmaxf(r0, 0.f);
            out[((long)b * NN + i0 + 1) * FF + f] = fmaxf(r1, 0.f);
        }
    }
}

extern "C" void kernel_launch(void* const* d_in, const int* in_sizes, int n_in,
                              void* d_out, int out_size, void* d_ws, size_t ws_size,
                              hipStream_t stream) {
    const float* x    = (const float*)d_in[0];
    const float* adj  = (const float*)d_in[1];
    const float* Wq   = (const float*)d_in[2];
    const float* bq   = (const float*)d_in[3];
    const float* Wk   = (const float*)d_in[4];
    const float* bk   = (const float*)d_in[5];
    const float* Wlin = (const float*)d_in[6];
    const float* blin = (const float*)d_in[7];
    const float* Wfc  = (const float*)d_in[8];
    const float* bfc  = (const float*)d_in[9];
    float* out = (float*)d_out;

    float* ws   = (float*)d_ws;
    float* dinv = ws;                 // 512
    float* psum = ws + 512;           // 16384
    float* T    = ws + 16896;         // 8192
    float* q_t  = ws + 25088;         // 2097152
    float* kT   = ws + 2122240;       // 2097152
    float* sxd  = ws + 4219392;       // 131072

    int nbpcu = 0;
    hipOccupancyMaxActiveBlocksPerMultiprocessor(&nbpcu, k_fused, 256, 0);
    if (nbpcu < 1) nbpcu = 1;
    long grid = (long)nbpcu * 256;    // 256 CUs on MI355X
    if (grid > 1024) grid = 1024;

    void* args[] = {(void*)&x, (void*)&adj, (void*)&Wq, (void*)&bq, (void*)&Wk,
                    (void*)&bk, (void*)&Wlin, (void*)&blin, (void*)&Wfc, (void*)&bfc,
                    (void*)&out, (void*)&dinv, (void*)&psum, (void*)&T,
                    (void*)&q_t, (void*)&kT, (void*)&sxd};
    hipLaunchCooperativeKernel((void*)k_fused, dim3((unsigned)grid), dim3(256),
                               args, 0, stream);
}

// Round 4
// 113.166 us; speedup vs baseline: 2.8109x; 2.8109x over previous
//
#include <hip/hip_runtime.h>
#include <math.h>

#define NN 512
#define FF 64
#define HH 4

// ---------------- ws layout (floats) ----------------
// dinv : [512]               off 0
// cvec : [512]               off 512
// T    : [B*H*N]   = 8192    off 1024
// q_t  : [B*H*N*F] = 2097152 off 9216
// kT   : [B*H*F*N] = 2097152 off 2106368
// sxd  : [B*N*F]   = 131072  off 4203520

// S1: q/k projection (1024 blocks, 4-row tiles, q XOR k per block)
//     + side jobs: dinv rows (blocks 0-511, wave 0), zero T (blocks 0-127,
//     wave 1), zero cvec (blocks 0-7, wave 2).
__global__ __launch_bounds__(256) void k_s1(const float* __restrict__ x,
                                            const float* __restrict__ Wq,
                                            const float* __restrict__ bq,
                                            const float* __restrict__ Wk,
                                            const float* __restrict__ bk,
                                            const float* __restrict__ adj,
                                            float* __restrict__ q_t,
                                            float* __restrict__ kT,
                                            float* __restrict__ dinv,
                                            float* __restrict__ T,
                                            float* __restrict__ cvec) {
    __shared__ float x_lds[4][64];
    int blk = blockIdx.x, tid = threadIdx.x;
    int wave = tid >> 6, lane = tid & 63;

    if (blk < 512 && wave == 0) {
        float acc = 0.f;
#pragma unroll
        for (int k = 0; k < 8; ++k) acc += adj[blk * NN + k * 64 + lane];
        for (int o = 32; o > 0; o >>= 1) acc += __shfl_xor(acc, o);
        if (lane == 0) dinv[blk] = 1.0f / sqrtf(acc + 1.0f);
    }
    if (blk < 128 && wave == 1) T[blk * 64 + lane] = 0.f;
    if (blk < 8 && wave == 2) cvec[blk * 64 + lane] = 0.f;

    int b = blk >> 8, rest = blk & 255, isK = rest >> 7, itile = rest & 127;
    int i0 = itile * 4;
    x_lds[tid >> 6][tid & 63] = x[((long)b * NN + i0 + (tid >> 6)) * FF + (tid & 63)];
    __syncthreads();
    const float* W = isK ? Wk : Wq;
    float bv = (isK ? bk : bq)[tid];
    float a0 = bv, a1 = bv, a2 = bv, a3 = bv;
    for (int cc = 0; cc < 64; ++cc) {
        float w = W[cc * 256 + tid];
        a0 = fmaf(x_lds[0][cc], w, a0);
        a1 = fmaf(x_lds[1][cc], w, a1);
        a2 = fmaf(x_lds[2][cc], w, a2);
        a3 = fmaf(x_lds[3][cc], w, a3);
    }
    int h = tid >> 6, f = tid & 63;
    int bh = b * HH + h;
    if (!isK) {
        long base = ((long)bh * NN + i0) * FF + f;
        q_t[base] = a0; q_t[base + FF] = a1;
        q_t[base + 2 * FF] = a2; q_t[base + 3 * FF] = a3;
    } else {
        long base = ((long)bh * FF + f) * NN + i0;  // i0%4==0 -> 16B aligned
        *(float4*)(kT + base) = make_float4(a0, a1, a2, a3);
    }
}

// S2: scores -> softmax -> noradj weighting -> atomicAdd into T.
//     Blocks with b==0,h==0 also accumulate cvec[j] = sum_i dinv_i*A[i,j]
//     (free: reuses the di*a products already computed).
//     1024 blocks, 8 i-rows each.
__global__ __launch_bounds__(256) void k_s2(const float* __restrict__ q_t,
                                            const float* __restrict__ kT,
                                            const float* __restrict__ adj,
                                            const float* __restrict__ dinv,
                                            float* __restrict__ T,
                                            float* __restrict__ cvec) {
    __shared__ float q_lds[8][64];
    __shared__ float red[8][4];
    __shared__ float red2[8][4];
    int blk = blockIdx.x, tid = threadIdx.x;
    int itile = blk & 63, h = (blk >> 6) & 3, b = blk >> 8;
    int bh = b * HH + h, i0 = itile * 8;
    int wv = tid >> 6, lane = tid & 63;
#pragma unroll
    for (int k = 0; k < 2; ++k) {
        int idx = k * 256 + tid;
        q_lds[idx >> 6][idx & 63] =
            q_t[((long)bh * NN + i0 + (idx >> 6)) * FF + (idx & 63)];
    }
    __syncthreads();
    int j0 = tid, j1 = tid + 256;
    const float* kb = kT + (long)bh * FF * NN;
    float s0[8], s1[8];
#pragma unroll
    for (int r = 0; r < 8; ++r) { s0[r] = 0.f; s1[r] = 0.f; }
#pragma unroll 2
    for (int f4 = 0; f4 < 64; f4 += 4) {
        float kv0[4], kv1[4];
#pragma unroll
        for (int u = 0; u < 4; ++u) {
            kv0[u] = kb[(f4 + u) * NN + j0];
            kv1[u] = kb[(f4 + u) * NN + j1];
        }
#pragma unroll
        for (int r = 0; r < 8; ++r) {
            float4 qv = *(const float4*)&q_lds[r][f4];
            s0[r] = fmaf(qv.x, kv0[0], s0[r]);
            s0[r] = fmaf(qv.y, kv0[1], s0[r]);
            s0[r] = fmaf(qv.z, kv0[2], s0[r]);
            s0[r] = fmaf(qv.w, kv0[3], s0[r]);
            s1[r] = fmaf(qv.x, kv1[0], s1[r]);
            s1[r] = fmaf(qv.y, kv1[1], s1[r]);
            s1[r] = fmaf(qv.z, kv1[2], s1[r]);
            s1[r] = fmaf(qv.w, kv1[3], s1[r]);
        }
    }
    const float scale = 0.125f;   // 1/sqrt(64)
    float m[8];
#pragma unroll
    for (int r = 0; r < 8; ++r) {
        float v = fmaxf(s0[r], s1[r]);
        for (int o = 32; o > 0; o >>= 1) v = fmaxf(v, __shfl_xor(v, o));
        if (lane == 0) red[r][wv] = v;
    }
    __syncthreads();
#pragma unroll
    for (int r = 0; r < 8; ++r)
        m[r] = fmaxf(fmaxf(red[r][0], red[r][1]), fmaxf(red[r][2], red[r][3]));
#pragma unroll
    for (int r = 0; r < 8; ++r) {
        s0[r] = expf((s0[r] - m[r]) * scale);
        s1[r] = expf((s1[r] - m[r]) * scale);
        float v = s0[r] + s1[r];
        for (int o = 32; o > 0; o >>= 1) v += __shfl_xor(v, o);
        if (lane == 0) red2[r][wv] = v;
    }
    __syncthreads();
    float dj0 = dinv[j0], dj1 = dinv[j1];
    float pw0 = 0.f, pw1 = 0.f, cw0 = 0.f, cw1 = 0.f;
#pragma unroll
    for (int r = 0; r < 8; ++r) {
        float Zi = 1.0f / (red2[r][0] + red2[r][1] + red2[r][2] + red2[r][3]);
        int gi = i0 + r;
        float di = dinv[gi];
        float a0 = adj[(long)gi * NN + j0] + (gi == j0 ? 1.f : 0.f);
        float a1 = adj[(long)gi * NN + j1] + (gi == j1 ? 1.f : 0.f);
        float t0 = di * a0, t1 = di * a1;
        pw0 = fmaf(t0, s0[r] * Zi, pw0);
        pw1 = fmaf(t1, s1[r] * Zi, pw1);
        cw0 += t0;
        cw1 += t1;
    }
    atomicAdd(&T[bh * NN + j0], pw0 * dj0);
    atomicAdd(&T[bh * NN + j1], pw1 * dj1);
    if (b == 0 && h == 0) {
        atomicAdd(&cvec[j0], cw0);
        atomicAdd(&cvec[j1], cw1);
    }
}

// S3: sxd[b,j,f] = x * (blin[f]*dinv_j*cvec[j] + sum_h T[b,h,j]*Wlin[h,f]) * dinv_j
__global__ __launch_bounds__(256) void k_s3(const float* __restrict__ x,
                                            const float* __restrict__ T,
                                            const float* __restrict__ Wlin,
                                            const float* __restrict__ blin,
                                            const float* __restrict__ cvec,
                                            const float* __restrict__ dinv,
                                            float* __restrict__ sxd) {
    int t = blockIdx.x * 256 + threadIdx.x;
    int f = t & 63, j = (t >> 6) & (NN - 1), b = t >> 15;
    float dj = dinv[j];
    float cj = dj * cvec[j];
    float S = blin[f] * cj;
#pragma unroll
    for (int h = 0; h < HH; ++h) S += T[(b * HH + h) * NN + j] * Wlin[h * FF + f];
    sxd[t] = x[t] * S * dj;
}

// S4: out[b,i,:] = relu((dinv_i * sum_j A[i,j]*sxd[b,j,:]) @ Wfc + bfc)
//     1024 blocks, 2 rows each, 4-way j-split, LDS combine + fused FC.
__global__ __launch_bounds__(256) void k_s4(const float* __restrict__ sxd,
                                            const float* __restrict__ adj,
                                            const float* __restrict__ dinv,
                                            const float* __restrict__ Wfc,
                                            const float* __restrict__ bfc,
                                            float* __restrict__ out) {
    __shared__ float part[4][2][64];
    __shared__ float m_lds[2][64];
    __shared__ float part2[4][2][64];
    int blk = blockIdx.x, tid = threadIdx.x;
    int b = blk >> 8, itile = blk & 255;
    int i0 = itile * 2;
    int f = tid & 63, jc = tid >> 6;
    const float* sb = sxd + (long)b * NN * FF + f;
    const float* ar0 = adj + (long)i0 * NN;
    const float* ar1 = ar0 + NN;
    float a0 = 0.f, a1 = 0.f;
    int jb = jc * 128;
#pragma unroll 8
    for (int j = jb; j < jb + 128; ++j) {
        float v = sb[(long)j * FF];
        a0 = fmaf(ar0[j], v, a0);
        a1 = fmaf(ar1[j], v, a1);
    }
    if ((i0 >> 7) == jc) a0 += sb[(long)i0 * FF];
    if (((i0 + 1) >> 7) == jc) a1 += sb[(long)(i0 + 1) * FF];
    part[jc][0][f] = a0;
    part[jc][1][f] = a1;
    __syncthreads();
    if (jc == 0) {
        m_lds[0][f] = (part[0][0][f] + part[1][0][f] + part[2][0][f] + part[3][0][f]) * dinv[i0];
        m_lds[1][f] = (part[0][1][f] + part[1][1][f] + part[2][1][f] + part[3][1][f]) * dinv[i0 + 1];
    }
    __syncthreads();
    float o0 = 0.f, o1 = 0.f;
    int c0 = jc * 16;
#pragma unroll
    for (int cc = 0; cc < 16; ++cc) {
        float w = Wfc[(c0 + cc) * FF + f];
        o0 = fmaf(m_lds[0][c0 + cc], w, o0);
        o1 = fmaf(m_lds[1][c0 + cc], w, o1);
    }
    part2[jc][0][f] = o0;
    part2[jc][1][f] = o1;
    __syncthreads();
    if (jc == 0) {
        float bb = bfc[f];
        float r0 = part2[0][0][f] + part2[1][0][f] + part2[2][0][f] + part2[3][0][f] + bb;
        float r1 = part2[0][1][f] + part2[1][1][f] + part2[2][1][f] + part2[3][1][f] + bb;
        out[((long)b * NN + i0) * FF + f]     = fmaxf(r0, 0.f);
        out[((long)b * NN + i0 + 1) * FF + f] = fmaxf(r1, 0.f);
    }
}

extern "C" void kernel_launch(void* const* d_in, const int* in_sizes, int n_in,
                              void* d_out, int out_size, void* d_ws, size_t ws_size,
                              hipStream_t stream) {
    const float* x    = (const float*)d_in[0];
    const float* adj  = (const float*)d_in[1];
    const float* Wq   = (const float*)d_in[2];
    const float* bq   = (const float*)d_in[3];
    const float* Wk   = (const float*)d_in[4];
    const float* bk   = (const float*)d_in[5];
    const float* Wlin = (const float*)d_in[6];
    const float* blin = (const float*)d_in[7];
    const float* Wfc  = (const float*)d_in[8];
    const float* bfc  = (const float*)d_in[9];
    float* out = (float*)d_out;

    float* ws   = (float*)d_ws;
    float* dinv = ws;                 // 512
    float* cvec = ws + 512;           // 512
    float* T    = ws + 1024;          // 8192
    float* q_t  = ws + 9216;          // 2097152
    float* kT   = ws + 2106368;       // 2097152
    float* sxd  = ws + 4203520;       // 131072

    k_s1<<<dim3(1024), dim3(256), 0, stream>>>(x, Wq, bq, Wk, bk, adj, q_t, kT, dinv, T, cvec);
    k_s2<<<dim3(1024), dim3(256), 0, stream>>>(q_t, kT, adj, dinv, T, cvec);
    k_s3<<<dim3(512), dim3(256), 0, stream>>>(x, T, Wlin, blin, cvec, dinv, sxd);
    k_s4<<<dim3(1024), dim3(256), 0, stream>>>(sxd, adj, dinv, Wfc, bfc, out);
}